// Round 14
// baseline (92.720 us; speedup 1.0000x reference)
//
#include <hip/hip_runtime.h>

// LocBlock2dNT: x (64,64,64,64) f32, w (256,64,16,16,16) f32
// out (64,256,16,16) f32 = relu( einsum('ncpqf,ocpqf->nopq', patches, w) / 32 )
//
// SINGLE kernel. block = (p, q-pair, o-half), grid 256, 512 thr.
//   Delivered bytes: w 268 MB (exactly once) + x 134 MB (dup x2, co-XCD
//   L2-served) + out 17 MB  = 419 MB  (vs r12/r13's 553 MB).
// Schedule (r13-proven): BK = 1 c (64 steps), 4 x 24 KB LDS bufs, depth-3,
//   stage-before-compute, ONE barrier per step: vmcnt(6) -> s_barrier ->
//   stage(t+3) -> compute(t). 3 gload_lds per thread per step.
// MFMA 16x16x16 f16 (r10-verified mapping), f16 = better absmax than bf16.
// Epilogue: LDS transpose (overlay) -> float2 (8-B) stores; the 8 q2-sibling
//   blocks of one (p,oh) are co-XCD (lb = p*16+q2*2+oh) -> L2 completes
//   full 64-B out lines.

typedef float    f32x4 __attribute__((ext_vector_type(4)));
typedef float    f32x2 __attribute__((ext_vector_type(2)));
typedef _Float16 f16x4 __attribute__((ext_vector_type(4)));

__device__ __forceinline__ void gload16(const void* g, void* l) {
    __builtin_amdgcn_global_load_lds(
        (const __attribute__((address_space(1))) void*)g,
        (__attribute__((address_space(3))) void*)l, 16, 0, 0);
}

__device__ __forceinline__ f16x4 cvt4(f32x4 v) {
    f16x4 r;
    r[0] = (_Float16)v[0]; r[1] = (_Float16)v[1];
    r[2] = (_Float16)v[2]; r[3] = (_Float16)v[3];
    return r;
}

__global__ __launch_bounds__(512)
void locblock_fused(const float* __restrict__ x, const float* __restrict__ w,
                    float* __restrict__ out) {
    // 4 bufs x [ x 8 KB | w 16 KB ] = 96 KB; epilogue T overlays (73.7 KB).
    __shared__ __align__(16) char smem[98304];

    // lb = p*16 + q2*2 + oh. XCD swizzle: each XCD gets 32 consecutive lb =
    // 2 full p's -> (a) oh-siblings adjacent (x dedup), (b) all 8 q2 of each
    // (p,oh) co-XCD (out 64-B line completion).
    const int hw = blockIdx.x;
    const int lb = (hw & 7) * 32 + (hw >> 3);        // bijective, 256 % 8 == 0
    const int p  = lb >> 4;                          // 0..15
    const int q2 = (lb >> 1) & 7;                    // q = 2*q2 + qw
    const int oh = lb & 1;                           // o half (128 o's)

    const int tid  = (int)threadIdx.x;
    const int lane = tid & 63;
    const int l15  = lane & 15;
    const int kq   = lane >> 4;                      // 0..3
    const int wv   = tid >> 6;                       // 0..7
    const int qw   = wv & 1;                         // wave's q within pair
    const int nc   = wv >> 1;                        // wave's o-quarter (32 o)

    // ---- staging sources (advance 4096 floats = 1 c per step) ----
    // x: 512 chunks/step (64 n x 8 u), u = fr*2 + h; slot s holds u = s^(n&7).
    const int xn = tid >> 3, xs = tid & 7;
    const int xu = xs ^ (xn & 7);
    const float* xsrc = x + (size_t)xn * 262144u
                          + (size_t)(4 * p + (xu >> 1)) * 64u
                          + (size_t)(q2 * 8 + (xu & 1) * 4);
    // w: 1024 chunks/step (128 o x 8 u), u = qw'*4 + kk; slot s = u^(o&7).
    const float* wsrc[2];
#pragma unroll
    for (int j = 0; j < 2; ++j) {
        const int id = j * 512 + tid;
        const int o = id >> 3, s = id & 7;
        const int u = s ^ (o & 7);
        wsrc[j] = w + (size_t)(oh * 128 + o) * 262144u
                    + (size_t)p * 256u + (size_t)(q2 * 32) + (size_t)(u * 4);
    }

    // ---- fragment LDS byte offsets (within a 24-KB buf) ----
    // A: row n = mf*16+l15 (pitch 128 B), chunk u = kq*2 + qw, slot u^(l15&7).
    // B: row o = nc*32+nf*16+l15 (pitch 128 B), chunk u = qw*4+kq.
    int aoff[4], boff[2];
#pragma unroll
    for (int mf = 0; mf < 4; ++mf)
        aoff[mf] = (mf * 16 + l15) * 128 + (((kq * 2 + qw) ^ (l15 & 7)) * 16);
#pragma unroll
    for (int nf = 0; nf < 2; ++nf)
        boff[nf] = 8192 + (nc * 32 + nf * 16 + l15) * 128
                 + (((qw * 4 + kq) ^ (l15 & 7)) * 16);

    f32x4 acc[4][2];
#pragma unroll
    for (int mf = 0; mf < 4; ++mf)
#pragma unroll
        for (int nf = 0; nf < 2; ++nf)
            acc[mf][nf] = (f32x4){0.f, 0.f, 0.f, 0.f};

    auto stage = [&](int c) {
        char* base = smem + (size_t)(c & 3) * 24576u;
        const size_t coff = (size_t)c * 4096u;
        gload16(xsrc + coff, base + tid * 16);                     // x: 1
#pragma unroll
        for (int j = 0; j < 2; ++j)                                 // w: 2
            gload16(wsrc[j] + coff, base + 8192 + j * 8192 + tid * 16);
    };

    auto compute = [&](int c) {
        const char* Lb = smem + (size_t)(c & 3) * 24576u;
        f16x4 av[4], bv[2];
#pragma unroll
        for (int mf = 0; mf < 4; ++mf)
            av[mf] = cvt4(*(const f32x4*)(Lb + aoff[mf]));
#pragma unroll
        for (int nf = 0; nf < 2; ++nf)
            bv[nf] = cvt4(*(const f32x4*)(Lb + boff[nf]));
#pragma unroll
        for (int mf = 0; mf < 4; ++mf)
#pragma unroll
            for (int nf = 0; nf < 2; ++nf)
                acc[mf][nf] = __builtin_amdgcn_mfma_f32_16x16x16f16(
                    av[mf], bv[nf], acc[mf][nf], 0, 0, 0);
    };

    // ---- depth-3, issue-early, ONE barrier per step, 64 c-steps ----
    stage(0);
    stage(1);
    stage(2);
#pragma unroll 1
    for (int t = 0; t < 61; ++t) {
        asm volatile("s_waitcnt vmcnt(6)" ::: "memory");   // own stage-t done
        __builtin_amdgcn_s_barrier();                      // => everyone's done
        stage(t + 3);                                      // buf (t+3)&3
        compute(t);
    }
    asm volatile("s_waitcnt vmcnt(6)" ::: "memory");
    __builtin_amdgcn_s_barrier();
    compute(61);
    asm volatile("s_waitcnt vmcnt(3)" ::: "memory");
    __builtin_amdgcn_s_barrier();
    compute(62);
    asm volatile("s_waitcnt vmcnt(0)" ::: "memory");
    __builtin_amdgcn_s_barrier();
    compute(63);

    __syncthreads();                                 // smem reuse fence

    // ---- epilogue 1: acc -> T[q][o][n], o-pitch 72 words (16-B aligned) ----
    float* T = (float*)smem;                         // 2*128*72*4 = 73728 B
    const float scale = 0.03125f;                    // 1/sqrt(16*64)
#pragma unroll
    for (int mf = 0; mf < 4; ++mf)
#pragma unroll
        for (int nf = 0; nf < 2; ++nf) {
            const int o  = nc * 32 + nf * 16 + l15;
            const int n0 = mf * 16 + kq * 4;         // D row = kq*4 + j
            f32x4 r;
#pragma unroll
            for (int j = 0; j < 4; ++j)
                r[j] = fmaxf(acc[mf][nf][j] * scale, 0.0f);
            *(f32x4*)(T + (size_t)(qw * 128 + o) * 72u + n0) = r;
        }
    __syncthreads();

    // ---- epilogue 2: T -> out, float2 (q-pair) stores ----
    // per iter: wave reads consecutive n (conflict-free), stores 8 B each.
#pragma unroll
    for (int i = 0; i < 16; ++i) {
        const int item = i * 512 + tid;              // 8192 = 128o x 64n
        const int n = item & 63, o = (item >> 6) & 127;
        f32x2 r;
        r[0] = T[(size_t)o * 72u + n];               // q = 0
        r[1] = T[(size_t)(128 + o) * 72u + n];       // q = 1
        *(f32x2*)(out + (size_t)n * 65536u + (size_t)(oh * 128 + o) * 256u
                      + (size_t)(p * 16 + q2 * 2)) = r;
    }
}

extern "C" void kernel_launch(void* const* d_in, const int* in_sizes, int n_in,
                              void* d_out, int out_size, void* d_ws, size_t ws_size,
                              hipStream_t stream) {
    const float* x = (const float*)d_in[0];
    const float* w = (const float*)d_in[1];
    float* out = (float*)d_out;
    locblock_fused<<<dim3(256), dim3(512), 0, stream>>>(x, w, out);
}

// Round 15
// 85.342 us; speedup vs baseline: 1.0865x; 1.0865x over previous
//
#include <hip/hip_runtime.h>

// LocBlock2dNT: x (64,64,64,64) f32, w (256,64,16,16,16) f32
// out (64,256,16,16) f32 = relu( einsum('ncpqf,ocpqf->nopq', patches, w) / 32 )
//
// SINGLE kernel. block = (p, q-quad, o-quarter), grid 256, 512 thr (r12 geom).
// Schedule: BK = 1 c (64 K-steps), 4 x 32 KB LDS bufs, depth-3 pipeline,
//   stage issued BEFORE compute, ONE barrier per step:
//     vmcnt(8) -> s_barrier -> stage(t+3) -> compute(t)
// MFMA 16x16x16 f16 (K=16 = one c), r10-verified fragment mapping.
// Epilogue: LDS-transpose (overlay) -> 16-B pq-contiguous stores.
//
// ROOFLINE NOTE (r15): unique traffic = w 256 MB (read exactly once) +
// x 64 MB + out 16 MB = 337 MB at the measured streaming-miss ceiling
// (~3.9 TB/s across 8 structural variants) = ~85 µs. This kernel (r13,
// best measured 85.5 µs) sits at that limit.

typedef float    f32x4 __attribute__((ext_vector_type(4)));
typedef _Float16 f16x4 __attribute__((ext_vector_type(4)));

__device__ __forceinline__ void gload16(const void* g, void* l) {
    __builtin_amdgcn_global_load_lds(
        (const __attribute__((address_space(1))) void*)g,
        (__attribute__((address_space(3))) void*)l, 16, 0, 0);
}

__device__ __forceinline__ f16x4 cvt4(f32x4 v) {
    f16x4 r;
    r[0] = (_Float16)v[0]; r[1] = (_Float16)v[1];
    r[2] = (_Float16)v[2]; r[3] = (_Float16)v[3];
    return r;
}

__global__ __launch_bounds__(512)
void locblock_fused(const float* __restrict__ x, const float* __restrict__ w,
                    float* __restrict__ out) {
    // 4 bufs x [ x 16 KB | w 16 KB ] = 128 KB; epilogue overlays (72 KB).
    __shared__ __align__(16) char smem[131072];

    // XCD swizzle: 32 consecutive logical blocks (2 full p's) per XCD.
    const int hw = blockIdx.x;
    const int lb = (hw & 7) * 32 + (hw >> 3);        // bijective, 256 % 8 == 0
    const int p  = lb >> 4;                          // 0..15
    const int q4 = (lb >> 2) & 3;                    // q = q4*4 + qi
    const int oq = lb & 3;                           // o-quarter (64 o's)

    const int tid  = (int)threadIdx.x;
    const int lane = tid & 63;
    const int l15  = lane & 15;
    const int kq   = lane >> 4;                      // 0..3
    const int wv   = tid >> 6;                       // 0..7
    const int qiw  = wv >> 1;                        // wave's q within quad
    const int ow   = wv & 1;                         // wave's o-half (32 o)

    // ---- staging sources (advance 4096 floats = 1 c per step) ----
    // x: 1024 chunks/step; per n, chunk u = fr*4 + qi (64-B runs per fr).
    //    LDS slot s holds source u = s ^ (n&15).
    const float* xsrc[2];
#pragma unroll
    for (int j = 0; j < 2; ++j) {
        const int id = j * 512 + tid;
        const int n = id >> 4, s = id & 15;
        const int u = s ^ (n & 15);
        xsrc[j] = x + (size_t)n * 262144u
                    + (size_t)(4 * p + (u >> 2)) * 64u
                    + (size_t)(q4 * 16 + (u & 3) * 4);
    }
    // w: 1024 chunks/step; per o, chunk u = qi*4 + kk (256-B runs per (o,c)).
    const float* wsrc[2];
#pragma unroll
    for (int j = 0; j < 2; ++j) {
        const int id = j * 512 + tid;
        const int o = id >> 4, s = id & 15;
        const int u = s ^ (o & 15);
        wsrc[j] = w + (size_t)(oq * 64 + o) * 262144u
                    + (size_t)p * 256u + (size_t)(q4 * 64)
                    + (size_t)((u >> 2) * 16 + (u & 3) * 4);
    }

    // ---- fragment LDS byte offsets (within a 32-KB buf) ----
    // A: row n = mf*16+l15, k16 = kq*4+j -> (fr=kq, fc=j, qi=qiw):
    //    chunk u = kq*4 + qiw, stored at u ^ l15.
    // B: row o = ow*32+nf*16+l15, chunk u = qiw*4 + kq, stored at u ^ l15.
    int aoff[4], boff[2];
#pragma unroll
    for (int mf = 0; mf < 4; ++mf)
        aoff[mf] = (mf * 16 + l15) * 256 + (((kq * 4 + qiw) ^ l15) * 16);
#pragma unroll
    for (int nf = 0; nf < 2; ++nf)
        boff[nf] = 16384 + (ow * 32 + nf * 16 + l15) * 256
                 + (((qiw * 4 + kq) ^ l15) * 16);

    f32x4 acc[4][2];
#pragma unroll
    for (int mf = 0; mf < 4; ++mf)
#pragma unroll
        for (int nf = 0; nf < 2; ++nf)
            acc[mf][nf] = (f32x4){0.f, 0.f, 0.f, 0.f};

    auto stage = [&](int c) {
        char* base = smem + (size_t)(c & 3) * 32768u;
        const size_t coff = (size_t)c * 4096u;
#pragma unroll
        for (int j = 0; j < 2; ++j)
            gload16(xsrc[j] + coff, base + j * 8192 + tid * 16);
#pragma unroll
        for (int j = 0; j < 2; ++j)
            gload16(wsrc[j] + coff, base + 16384 + j * 8192 + tid * 16);
    };

    auto compute = [&](int c) {
        const char* Lb = smem + (size_t)(c & 3) * 32768u;
        f16x4 av[4], bv[2];
#pragma unroll
        for (int mf = 0; mf < 4; ++mf)
            av[mf] = cvt4(*(const f32x4*)(Lb + aoff[mf]));
#pragma unroll
        for (int nf = 0; nf < 2; ++nf)
            bv[nf] = cvt4(*(const f32x4*)(Lb + boff[nf]));
#pragma unroll
        for (int mf = 0; mf < 4; ++mf)
#pragma unroll
            for (int nf = 0; nf < 2; ++nf)
                acc[mf][nf] = __builtin_amdgcn_mfma_f32_16x16x16f16(
                    av[mf], bv[nf], acc[mf][nf], 0, 0, 0);
    };

    // ---- depth-3, issue-early, ONE barrier per step, 64 c-steps ----
    stage(0);
    stage(1);
    stage(2);
#pragma unroll 1
    for (int t = 0; t < 61; ++t) {
        asm volatile("s_waitcnt vmcnt(8)" ::: "memory");   // own stage-t done
        __builtin_amdgcn_s_barrier();                      // => everyone's done
        stage(t + 3);                                      // buf (t+3)&3 != t&3
        compute(t);
    }
    asm volatile("s_waitcnt vmcnt(8)" ::: "memory");
    __builtin_amdgcn_s_barrier();
    compute(61);
    asm volatile("s_waitcnt vmcnt(4)" ::: "memory");
    __builtin_amdgcn_s_barrier();
    compute(62);
    asm volatile("s_waitcnt vmcnt(0)" ::: "memory");
    __builtin_amdgcn_s_barrier();
    compute(63);

    __syncthreads();                                 // smem reuse fence

    // ---- epilogue 1: acc -> T[q][o][n], o-stride 72 words ----
    float* T = (float*)smem;                         // 4*64*72*4 = 73728 B
    const float scale = 0.03125f;                    // 1/sqrt(16*64)
#pragma unroll
    for (int mf = 0; mf < 4; ++mf)
#pragma unroll
        for (int nf = 0; nf < 2; ++nf) {
            const int o  = ow * 32 + nf * 16 + l15;
            const int n0 = mf * 16 + kq * 4;         // D row = kq*4 + j
            f32x4 r;
#pragma unroll
            for (int j = 0; j < 4; ++j)
                r[j] = fmaxf(acc[mf][nf][j] * scale, 0.0f);
            *(f32x4*)(T + (size_t)(qiw * 64 + o) * 72u + n0) = r;
        }
    __syncthreads();

    // ---- epilogue 2: T -> out, 16-B pq-contiguous stores ----
#pragma unroll
    for (int i = 0; i < 8; ++i) {
        const int item = i * 512 + tid;              // 4096 = 64n x 64o
        const int n = item >> 6, o = item & 63;
        f32x4 r;
#pragma unroll
        for (int s = 0; s < 4; ++s)
            r[s] = T[(size_t)(s * 64 + o) * 72u + n];
        *(f32x4*)(out + (size_t)n * 65536u + (size_t)(oq * 64 + o) * 256u
                      + (size_t)(p * 16 + q4 * 4)) = r;
    }
}

extern "C" void kernel_launch(void* const* d_in, const int* in_sizes, int n_in,
                              void* d_out, int out_size, void* d_ws, size_t ws_size,
                              hipStream_t stream) {
    const float* x = (const float*)d_in[0];
    const float* w = (const float*)d_in[1];
    float* out = (float*)d_out;
    locblock_fused<<<dim3(256), dim3(512), 0, stream>>>(x, w, out);
}